// Round 6
// baseline (336.419 us; speedup 1.0000x reference)
//
#include <hip/hip_runtime.h>
#include <math.h>

#define NE 8      // experts
#define ND 512    // features
#define NH 2048   // hidden
#define NT 2048   // tokens = B*S
#define MAXIT 40  // max (expert, m-tile) items: 2048/64 + 8 partials

typedef __attribute__((ext_vector_type(8))) short short8;   // 8 bf16 = 4 VGPRs
typedef __attribute__((ext_vector_type(4))) float f32x4;    // MFMA accumulator

#define GLL(g, d) __builtin_amdgcn_global_load_lds( \
    (const __attribute__((address_space(1))) void*)(g), \
    (__attribute__((address_space(3))) void*)(d), 16, 0, 0)

__device__ __forceinline__ unsigned short f2bf(float x) {
    unsigned int u = __builtin_bit_cast(unsigned int, x);
    u += 0x7FFFu + ((u >> 16) & 1u);            // round-to-nearest-even
    return (unsigned short)(u >> 16);
}

__device__ __forceinline__ short8 lds8(const unsigned short* p) {
    return *(const short8*)p;
}

// ---------------- gating (fp32, exact argmax semantics) + x->bf16 fused ----
__global__ __launch_bounds__(256) void gate_kernel(
    const float* __restrict__ xr, const float* __restrict__ xi,
    const float* __restrict__ gW, const float* __restrict__ gb,
    float* __restrict__ gate_w,
    int* __restrict__ counts, int* __restrict__ tok_list,
    unsigned short* __restrict__ obr, unsigned short* __restrict__ obi)
{
    int t = blockIdx.x;
    int tid = threadIdx.x;
    const float* xrt = xr + (size_t)t * ND;
    const float* xit = xi + (size_t)t * ND;

    // fused bf16 conversion of this token's row (L1-hot with the gating reads)
    #pragma unroll
    for (int d = tid; d < ND; d += 256) {
        obr[(size_t)t * ND + d] = f2bf(xrt[d]);
        obi[(size_t)t * ND + d] = f2bf(xit[d]);
    }

    float acc[NE] = {0,0,0,0,0,0,0,0};
    for (int r = tid; r < 2 * ND; r += 256) {
        int d = r & (ND - 1);
        float a = xrt[d], b = xit[d];
        float v = (r < ND) ? sqrtf(a * a + b * b) : atan2f(b, a);
        const float4* g = (const float4*)(gW + (size_t)r * NE);
        float4 g0 = g[0], g1 = g[1];
        acc[0] += v * g0.x; acc[1] += v * g0.y; acc[2] += v * g0.z; acc[3] += v * g0.w;
        acc[4] += v * g1.x; acc[5] += v * g1.y; acc[6] += v * g1.z; acc[7] += v * g1.w;
    }
    #pragma unroll
    for (int e = 0; e < NE; e++) {
        for (int off = 32; off > 0; off >>= 1)
            acc[e] += __shfl_down(acc[e], off, 64);
    }
    __shared__ float part[4][NE];
    int wave = tid >> 6, lane = tid & 63;
    if (lane == 0) {
        #pragma unroll
        for (int e = 0; e < NE; e++) part[wave][e] = acc[e];
    }
    __syncthreads();
    if (tid == 0) {
        float s[NE];
        #pragma unroll
        for (int e = 0; e < NE; e++)
            s[e] = part[0][e] + part[1][e] + part[2][e] + part[3][e] + gb[e];
        int amax = 0; float m = s[0];
        #pragma unroll
        for (int e = 1; e < NE; e++) if (s[e] > m) { m = s[e]; amax = e; }
        float denom = 0.f;
        #pragma unroll
        for (int e = 0; e < NE; e++) denom += expf(s[e] - m);
        gate_w[t] = 1.0f / denom;
        int pos = atomicAdd(&counts[amax], 1);
        tok_list[amax * NT + pos] = t;
    }
}

// ---------------- fused weight transpose + bf16 (W1 and W2 in one launch) ----
// src fp32 [e][R][C] -> dst bf16 [e][C][R]; z = e + 8*which.
// float4 loads, bf16 convert BEFORE LDS, transposed 9.2 KB LDS tile,
// contiguous ds_read_b128 + short8 stores. Block (0,0,0) zeroes counts.
__global__ __launch_bounds__(256) void transw_kernel(
    const float* __restrict__ W1r, unsigned short* __restrict__ w1tr,
    const float* __restrict__ W1i, unsigned short* __restrict__ w1ti,
    const float* __restrict__ W2r, unsigned short* __restrict__ w2tr,
    const float* __restrict__ W2i, unsigned short* __restrict__ w2ti,
    int* __restrict__ counts)
{
    __shared__ unsigned short tile[64][72];   // [col][row], +8 pad
    int z = blockIdx.z;
    int e = z & 7, which = z >> 3;
    if (z == 0 && blockIdx.x == 0 && blockIdx.y == 0 && threadIdx.x < 16)
        counts[threadIdx.x] = 0;
    int R = which ? NH : ND;
    int C = which ? ND : NH;
    int c0 = (which ? blockIdx.y : blockIdx.x) * 64;
    int r0 = (which ? blockIdx.x : blockIdx.y) * 64;
    const float* s0 = which ? W2r : W1r;
    const float* s1 = which ? W2i : W1i;
    unsigned short* d0 = which ? w2tr : w1tr;
    unsigned short* d1 = which ? w2ti : w1ti;
    size_t off = (size_t)e * R * C;
    int tid = threadIdx.x;
    #pragma unroll
    for (int p = 0; p < 2; ++p) {
        const float* src = (p ? s1 : s0) + off;
        unsigned short* dst = (p ? d1 : d0) + off;
        if (p) __syncthreads();
        #pragma unroll
        for (int i = 0; i < 4; ++i) {
            int r = i * 16 + (tid >> 4);
            int c4 = (tid & 15) * 4;
            float4 v = *(const float4*)&src[(size_t)(r0 + r) * C + c0 + c4];
            tile[c4 + 0][r] = f2bf(v.x);
            tile[c4 + 1][r] = f2bf(v.y);
            tile[c4 + 2][r] = f2bf(v.z);
            tile[c4 + 3][r] = f2bf(v.w);
        }
        __syncthreads();
        #pragma unroll
        for (int i = 0; i < 2; ++i) {
            int c = i * 32 + (tid >> 3);
            int r8 = (tid & 7) * 8;
            short8 v = *(const short8*)&tile[c][r8];
            *(short8*)&dst[(size_t)(c0 + c) * R + r0 + r8] = v;
        }
    }
}

// ---------------- shared GEMM machinery: 4-deep LDS ring pipeline ----------
// 128 KiB LDS (guide-verified on gfx950): 4 ring slots x {Ar,Ai,Br,Bi} x 8KB.
// Prefetch 3 K-steps ahead; steady state vmcnt(16) completes only the oldest
// step's 8 loads while 16 ride across barriers => ~3 compute phases (~900cyc)
// of HBM latency cover. ONE barrier per K-step: at the barrier all waves have
// finished compute(t-1), whose slot ((t-1)&3 == (t+3)&3) STAGE then overwrites.
// LDS XOR swizzle unchanged: physical k-chunk = logical ^ (row & 7), applied
// on the global-source side of GLL (LDS slot order fixed to lane order).

#define VMW16 asm volatile("s_waitcnt vmcnt(16)" ::: "memory")
#define VMW8  asm volatile("s_waitcnt vmcnt(8)"  ::: "memory")
#define VMW0  asm volatile("s_waitcnt vmcnt(0)"  ::: "memory")
#define BARX do {                            \
    __builtin_amdgcn_sched_barrier(0);       \
    __builtin_amdgcn_s_barrier();            \
    __builtin_amdgcn_sched_barrier(0);       \
} while (0)
#define SP1 __builtin_amdgcn_s_setprio(1)
#define SP0 __builtin_amdgcn_s_setprio(0)

#define RING_DECL __shared__ alignas(16) unsigned short ring[4][16384];

#define STAGE_S(s, ko) do {                                  \
    unsigned short* _b = &ring[s][0];                        \
    GLL(gAr0 + (ko), _b + (w * 16) * 64);                    \
    GLL(gAr1 + (ko), _b + (w * 16 + 8) * 64);                \
    GLL(gAi0 + (ko), _b + 4096 + (w * 16) * 64);             \
    GLL(gAi1 + (ko), _b + 4096 + (w * 16 + 8) * 64);         \
    GLL(gBr0 + (ko), _b + 8192 + (w * 16) * 64);             \
    GLL(gBr1 + (ko), _b + 8192 + (w * 16 + 8) * 64);         \
    GLL(gBi0 + (ko), _b + 12288 + (w * 16) * 64);            \
    GLL(gBi1 + (ko), _b + 12288 + (w * 16 + 8) * 64);        \
} while (0)

// 4 independent accumulators (RR, II, RI, IR): no VALU in the hot loop,
// 16 independent MFMA dep chains. Combined in epilogue: r = RR-II, i = RI+IR.
#define COMPUTE_S(s) do {                                                        \
    const unsigned short* _sa = &ring[s][0];                                     \
    _Pragma("unroll")                                                            \
    for (int ks = 0; ks < 2; ++ks) {                                             \
        int pa = ((ks * 4 + quad) ^ (l15 & 7)) * 8;                              \
        short8 br  = lds8(_sa + 8192  + (w * 16 + l15) * 64 + pa);               \
        short8 bi2 = lds8(_sa + 12288 + (w * 16 + l15) * 64 + pa);               \
        _Pragma("unroll")                                                        \
        for (int m = 0; m < 4; ++m) {                                            \
            short8 ar  = lds8(_sa + (m * 16 + l15) * 64 + pa);                   \
            short8 ai2 = lds8(_sa + 4096 + (m * 16 + l15) * 64 + pa);            \
            aRR[m] = __builtin_amdgcn_mfma_f32_16x16x32_bf16(ar,  br,  aRR[m], 0, 0, 0); \
            aII[m] = __builtin_amdgcn_mfma_f32_16x16x32_bf16(ai2, bi2, aII[m], 0, 0, 0); \
            aRI[m] = __builtin_amdgcn_mfma_f32_16x16x32_bf16(ar,  bi2, aRI[m], 0, 0, 0); \
            aIR[m] = __builtin_amdgcn_mfma_f32_16x16x32_bf16(ai2, br,  aIR[m], 0, 0, 0); \
        }                                                                        \
    }                                                                            \
} while (0)

// NK >= 4. Steady: vmcnt(16)->barrier->STAGE(t+3)->MFMA(t). Tail drains 16/8/0.
#define PIPE_RING(NK) do {                                                   \
    STAGE_S(0, 0); STAGE_S(1, 64); STAGE_S(2, 128);                          \
    _Pragma("unroll 1")                                                      \
    for (int t = 0; t < (NK) - 3; ++t) {                                     \
        VMW16; BARX;                                                         \
        STAGE_S((t + 3) & 3, (t + 3) * 64);                                  \
        SP1; COMPUTE_S(t & 3); SP0;                                          \
    }                                                                        \
    VMW16; BARX; SP1; COMPUTE_S(((NK) - 3) & 3); SP0;                        \
    VMW8;  BARX; SP1; COMPUTE_S(((NK) - 2) & 3); SP0;                        \
    VMW0;  BARX; SP1; COMPUTE_S(((NK) - 1) & 3); SP0;                        \
} while (0)

// item derivation: block's item index -> (expert e, m-tile mt) via prefix
// scan over ceil(counts[e]/64). Returns false if item beyond total work.
__device__ __forceinline__ bool find_item(const int* counts, int item,
                                          int& e, int& mt, int& n) {
    int rem = item;
    for (e = 0; e < NE; ++e) {
        n = counts[e];
        int m = (n + 63) >> 6;
        if (rem < m) { mt = rem; return true; }
        rem -= m;
    }
    return false;
}

// ---------------- stage 1: complex D->H, 4-deep ring -> h bf16 -------------
// bid decode groups all 32 n-tiles of an item on one XCD (bid%8 heuristic):
// x=bid&7, t=bid>>3, nt=t&31, item=(t>>5)*8+x  => item%8 == bid%8.
__global__ __launch_bounds__(256, 1) void moe1_kernel(
    const unsigned short* __restrict__ xbr, const unsigned short* __restrict__ xbi,
    const unsigned short* __restrict__ w1tr, const unsigned short* __restrict__ w1ti,
    const float* __restrict__ b1r, const float* __restrict__ b1i,
    const float* __restrict__ mod_b,
    const int* __restrict__ counts, const int* __restrict__ tok_list,
    unsigned short* __restrict__ hr, unsigned short* __restrict__ hi)
{
    int bid = blockIdx.x;
    int xg = bid & 7, tg = bid >> 3;
    int nt = tg & 31;
    int item = (tg >> 5) * 8 + xg;
    int e, mt, n;
    if (!find_item(counts, item, e, mt, n)) return;
    int mbase = mt * 64, n0 = nt * 64;

    int tid = threadIdx.x;
    int w = tid >> 6, l = tid & 63;
    int l15 = l & 15, quad = l >> 4;
    int swz = (((l & 7) ^ ((l >> 3) & 7)) * 8);

    RING_DECL

    const int* tl = tok_list + e * NT;
    int ia0 = mbase + w * 16 + (l >> 3);
    int ia1 = ia0 + 8;
    int ra0 = tl[ia0 < n ? ia0 : n - 1];
    int ra1 = tl[ia1 < n ? ia1 : n - 1];
    const unsigned short* gAr0 = xbr + (size_t)ra0 * ND + swz;
    const unsigned short* gAi0 = xbi + (size_t)ra0 * ND + swz;
    const unsigned short* gAr1 = xbr + (size_t)ra1 * ND + swz;
    const unsigned short* gAi1 = xbi + (size_t)ra1 * ND + swz;
    size_t brow = (size_t)e * NH + n0 + w * 16 + (l >> 3);
    const unsigned short* gBr0 = w1tr + brow * ND + swz;
    const unsigned short* gBr1 = w1tr + (brow + 8) * ND + swz;
    const unsigned short* gBi0 = w1ti + brow * ND + swz;
    const unsigned short* gBi1 = w1ti + (brow + 8) * ND + swz;

    f32x4 aRR[4] = {}, aII[4] = {}, aRI[4] = {}, aIR[4] = {};

    PIPE_RING(ND / 64);   // 8 K-steps

    // epilogue: C/D layout col = lane&15 (N), row = quad*4 + r (M)
    int col = n0 + w * 16 + l15;
    float bre = b1r[(size_t)e * NH + col];
    float bie = b1i[(size_t)e * NH + col];
    float mbv = mod_b[(size_t)e * NH + col];
    #pragma unroll
    for (int m = 0; m < 4; ++m) {
        #pragma unroll
        for (int r = 0; r < 4; ++r) {
            int tix = m * 16 + quad * 4 + r;
            if (mbase + tix >= n) continue;
            int tok = tl[mbase + tix];
            float vr = aRR[m][r] - aII[m][r] + bre;
            float vi = aRI[m][r] + aIR[m][r] + bie;
            float a = sqrtf(vr * vr + vi * vi + 1e-10f);
            float sc = fmaxf(a + mbv, 0.0f) / (a + 1e-10f);
            hr[(size_t)tok * NH + col] = f2bf(vr * sc);
            hi[(size_t)tok * NH + col] = f2bf(vi * sc);
        }
    }
}

// ---------------- stage 2: complex H->D, FULL K=2048, 4-deep ring ----------
// Top-1 routing => each (token,col) owned by exactly one block => plain stores.
// bid decode: x=bid&7, t=bid>>3, nt=t&7, item=(t>>3)*8+x (item's 8 n-tiles
// share one XCD => A-panel (512KB) L2-resident, fetched once per item).
__global__ __launch_bounds__(256, 1) void moe2_kernel(
    const unsigned short* __restrict__ hr, const unsigned short* __restrict__ hi,
    const unsigned short* __restrict__ w2tr, const unsigned short* __restrict__ w2ti,
    const float* __restrict__ b2r, const float* __restrict__ b2i,
    const int* __restrict__ counts, const int* __restrict__ tok_list,
    const float* __restrict__ gate_w,
    float* __restrict__ out)
{
    int bid = blockIdx.x;
    int xg = bid & 7, tg = bid >> 3;
    int nt = tg & 7;
    int item = (tg >> 3) * 8 + xg;
    int e, mt, n;
    if (!find_item(counts, item, e, mt, n)) return;
    int mbase = mt * 64, n0 = nt * 64;

    int tid = threadIdx.x;
    int w = tid >> 6, l = tid & 63;
    int l15 = l & 15, quad = l >> 4;
    int swz = (((l & 7) ^ ((l >> 3) & 7)) * 8);

    RING_DECL

    const int* tl = tok_list + e * NT;
    int ia0 = mbase + w * 16 + (l >> 3);
    int ia1 = ia0 + 8;
    int ra0 = tl[ia0 < n ? ia0 : n - 1];
    int ra1 = tl[ia1 < n ? ia1 : n - 1];
    const unsigned short* gAr0 = hr + (size_t)ra0 * NH + swz;
    const unsigned short* gAi0 = hi + (size_t)ra0 * NH + swz;
    const unsigned short* gAr1 = hr + (size_t)ra1 * NH + swz;
    const unsigned short* gAi1 = hi + (size_t)ra1 * NH + swz;
    size_t brow = (size_t)e * ND + n0 + w * 16 + (l >> 3);
    const unsigned short* gBr0 = w2tr + brow * NH + swz;
    const unsigned short* gBr1 = w2tr + (brow + 8) * NH + swz;
    const unsigned short* gBi0 = w2ti + brow * NH + swz;
    const unsigned short* gBi1 = w2ti + (brow + 8) * NH + swz;

    f32x4 aRR[4] = {}, aII[4] = {}, aRI[4] = {}, aIR[4] = {};

    PIPE_RING(NH / 64);   // 32 K-steps, full K

    int col = n0 + w * 16 + l15;
    float bre = b2r[(size_t)e * ND + col];
    float bie = b2i[(size_t)e * ND + col];
    #pragma unroll
    for (int m = 0; m < 4; ++m) {
        #pragma unroll
        for (int r = 0; r < 4; ++r) {
            int tix = m * 16 + quad * 4 + r;
            if (mbase + tix >= n) continue;
            int tok = tl[mbase + tix];
            float gw = gate_w[tok];
            out[(size_t)tok * ND + col] = (aRR[m][r] - aII[m][r] + bre) * gw;
            out[(size_t)NT * ND + (size_t)tok * ND + col] = (aRI[m][r] + aIR[m][r] + bie) * gw;
        }
    }
}

extern "C" void kernel_launch(void* const* d_in, const int* in_sizes, int n_in,
                              void* d_out, int out_size, void* d_ws, size_t ws_size,
                              hipStream_t stream) {
    const float* xr   = (const float*)d_in[0];
    const float* xi   = (const float*)d_in[1];
    const float* gW   = (const float*)d_in[2];
    const float* gb   = (const float*)d_in[3];
    const float* W1r  = (const float*)d_in[4];
    const float* W1i  = (const float*)d_in[5];
    const float* b1r  = (const float*)d_in[6];
    const float* b1i  = (const float*)d_in[7];
    const float* modb = (const float*)d_in[8];
    const float* W2r  = (const float*)d_in[9];
    const float* W2i  = (const float*)d_in[10];
    const float* b2r  = (const float*)d_in[11];
    const float* b2i  = (const float*)d_in[12];
    float* out = (float*)d_out;

    char* ws = (char*)d_ws;
    int*   counts   = (int*)ws;                              // zeroed by transw block (0,0,0)
    float* gate_w   = (float*)(ws + 256);                    // NT*4
    int*   tok_list = (int*)(ws + 256 + 8192);               // NE*NT*4
    size_t off = 256 + 8192 + (size_t)NE * NT * 4;
    unsigned short* xbr  = (unsigned short*)(ws + off); off += (size_t)NT * ND * 2;
    unsigned short* xbi  = (unsigned short*)(ws + off); off += (size_t)NT * ND * 2;
    unsigned short* w1tr = (unsigned short*)(ws + off); off += (size_t)NE * ND * NH * 2;
    unsigned short* w1ti = (unsigned short*)(ws + off); off += (size_t)NE * ND * NH * 2;
    unsigned short* w2tr = (unsigned short*)(ws + off); off += (size_t)NE * ND * NH * 2;
    unsigned short* w2ti = (unsigned short*)(ws + off); off += (size_t)NE * ND * NH * 2;
    unsigned short* h_r  = (unsigned short*)(ws + off); off += (size_t)NT * NH * 2;
    unsigned short* h_i  = (unsigned short*)(ws + off); off += (size_t)NT * NH * 2;

    // transw first (independent of gating; zeroes counts before gate runs).
    transw_kernel<<<dim3(32, 8, 16), 256, 0, stream>>>(
        W1r, w1tr, W1i, w1ti, W2r, w2tr, W2i, w2ti, counts);
    gate_kernel<<<NT, 256, 0, stream>>>(xr, xi, gW, gb, gate_w, counts, tok_list, xbr, xbi);
    moe1_kernel<<<8 * 32 * (MAXIT / 8), 256, 0, stream>>>(
        xbr, xbi, w1tr, w1ti, b1r, b1i, modb, counts, tok_list, h_r, h_i);
    moe2_kernel<<<8 * 8 * (MAXIT / 8), 256, 0, stream>>>(
        h_r, h_i, w2tr, w2ti, b2r, b2i, counts, tok_list, gate_w, out);
}